// Round 1
// baseline (494.250 us; speedup 1.0000x reference)
//
#include <hip/hip_runtime.h>
#include <hip/hip_bf16.h>

#define B_ 8
#define H_ 8
#define S_ 1024
#define D_ 64

typedef __attribute__((ext_vector_type(8))) short bf16x8;
typedef __attribute__((ext_vector_type(4))) float f32x4;

__device__ __forceinline__ short f2bf(float f) {
  union { float f; unsigned u; } x; x.f = f;
  unsigned r = (x.u + 0x7FFFu + ((x.u >> 16) & 1u)) >> 16;
  return (short)r;
}

__device__ __forceinline__ bf16x8 load8_bf(const float* p) {
  float4 a = *(const float4*)p;
  float4 b = *(const float4*)(p + 4);
  bf16x8 f;
  f[0] = f2bf(a.x); f[1] = f2bf(a.y); f[2] = f2bf(a.z); f[3] = f2bf(a.w);
  f[4] = f2bf(b.x); f[5] = f2bf(b.y); f[6] = f2bf(b.z); f[7] = f2bf(b.w);
  return f;
}

constexpr int QT  = 16;            // q rows per workgroup
constexpr int NW  = 4;             // waves per workgroup
constexpr int TPW = (S_ / 16) / NW; // 16 k-tiles per wave
constexpr int PPAD = 8;            // bf16 pad on P rows (16B)

// Fused attention: scores (reg-resident) -> softmax -> attn global write +
// P(bf16) to LDS -> PV MFMA -> O.
__global__ __launch_bounds__(256) void attn_fused(
    const float* __restrict__ Q, const float* __restrict__ K,
    const float* __restrict__ V, float* __restrict__ O,
    float* __restrict__ A)
{
  const int bh   = blockIdx.y;
  const int q0   = blockIdx.x * QT;
  const int tid  = threadIdx.x;
  const int wave = tid >> 6;
  const int lane = tid & 63;
  const int m    = lane & 15;   // col within 16-tile / A-frag row
  const int quad = lane >> 4;   // 0..3

  const float* Qb = Q + (size_t)bh * S_ * D_;
  const float* Kb = K + (size_t)bh * S_ * D_;
  const float* Vb = V + (size_t)bh * S_ * D_;
  float* Ob = O + (size_t)bh * S_ * D_;
  float* Ab = A + (size_t)bh * S_ * S_;

  __shared__ float redmax[NW][QT];
  __shared__ float redsum[NW][QT];
  __shared__ short pbuf[QT][S_ + PPAD];  // bf16 P, row stride 1032 (516 dwords)

  // ---- Q fragments: A[m][k=quad*8+j (+32)] -> 8 consecutive d per lane ----
  bf16x8 qf0, qf1;
  {
    const float* qp = Qb + (size_t)(q0 + m) * D_ + quad * 8;
    qf0 = load8_bf(qp);
    qf1 = load8_bf(qp + 32);
  }

  // ---- scores: wave w owns k-tiles {w, w+4, ..., w+60} ----
  f32x4 acc[TPW];
  #pragma unroll
  for (int t = 0; t < TPW; ++t) {
    const int kt = t * NW + wave;
    const float* kp = Kb + (size_t)(kt * 16 + m) * D_ + quad * 8;
    bf16x8 kf0 = load8_bf(kp);
    bf16x8 kf1 = load8_bf(kp + 32);
    f32x4 c = {0.f, 0.f, 0.f, 0.f};
    c = __builtin_amdgcn_mfma_f32_16x16x32_bf16(qf0, kf0, c, 0, 0, 0);
    c = __builtin_amdgcn_mfma_f32_16x16x32_bf16(qf1, kf1, c, 0, 0, 0);
    acc[t] = c * 0.125f;  // 1/sqrt(64)
  }

  // ---- row max: C layout row = quad*4+reg, col = m; reduce over 16 lanes ----
  float tmp4[4];
  #pragma unroll
  for (int r = 0; r < 4; ++r) {
    float v = acc[0][r];
    #pragma unroll
    for (int t = 1; t < TPW; ++t) v = fmaxf(v, acc[t][r]);
    v = fmaxf(v, __shfl_xor(v, 1));
    v = fmaxf(v, __shfl_xor(v, 2));
    v = fmaxf(v, __shfl_xor(v, 4));
    v = fmaxf(v, __shfl_xor(v, 8));
    tmp4[r] = v;
  }
  if (m == 0) {
    #pragma unroll
    for (int r = 0; r < 4; ++r) redmax[wave][quad * 4 + r] = tmp4[r];
  }
  __syncthreads();

  // ---- exp + row sum ----
  #pragma unroll
  for (int r = 0; r < 4; ++r) {
    const int row = quad * 4 + r;
    const float gm = fmaxf(fmaxf(redmax[0][row], redmax[1][row]),
                           fmaxf(redmax[2][row], redmax[3][row]));
    float s = 0.f;
    #pragma unroll
    for (int t = 0; t < TPW; ++t) {
      float p = __builtin_exp2f((acc[t][r] - gm) * 1.4426950408889634f);
      acc[t][r] = p;
      s += p;
    }
    s += __shfl_xor(s, 1);
    s += __shfl_xor(s, 2);
    s += __shfl_xor(s, 4);
    s += __shfl_xor(s, 8);
    tmp4[r] = s;
  }
  if (m == 0) {
    #pragma unroll
    for (int r = 0; r < 4; ++r) redsum[wave][quad * 4 + r] = tmp4[r];
  }
  __syncthreads();

  float rinv[4];
  #pragma unroll
  for (int r = 0; r < 4; ++r) {
    const int row = quad * 4 + r;
    const float tot = (redsum[0][row] + redsum[1][row]) +
                      (redsum[2][row] + redsum[3][row]);
    rinv[r] = 1.f / tot;
  }

  // ---- normalize: write attn (global, once) + P bf16 to LDS ----
  #pragma unroll
  for (int t = 0; t < TPW; ++t) {
    const int kt = t * NW + wave;
    #pragma unroll
    for (int r = 0; r < 4; ++r) {
      const int row = quad * 4 + r;
      const float p = acc[t][r] * rinv[r];
      Ab[(size_t)(q0 + row) * S_ + kt * 16 + m] = p;
      pbuf[row][kt * 16 + m] = f2bf(p);
    }
  }
  __syncthreads();

  // ---- O = P · V : wave w owns d-cols [16w, 16w+16) ----
  f32x4 oc = {0.f, 0.f, 0.f, 0.f};
  const int n0 = wave * 16;
  for (int kc = 0; kc < S_ / 32; ++kc) {
    // A frag: P[m][kc*32 + quad*8 + j], 16B-aligned ds_read_b128
    bf16x8 af = *(const bf16x8*)&pbuf[m][kc * 32 + quad * 8];
    // B frag: V[kc*32 + quad*8 + j][n0 + m]
    const float* vp = Vb + (size_t)(kc * 32 + quad * 8) * D_ + n0 + m;
    bf16x8 bv;
    #pragma unroll
    for (int j = 0; j < 8; ++j) bv[j] = f2bf(vp[(size_t)j * D_]);
    oc = __builtin_amdgcn_mfma_f32_16x16x32_bf16(af, bv, oc, 0, 0, 0);
  }
  #pragma unroll
  for (int r = 0; r < 4; ++r) {
    Ob[(size_t)(q0 + quad * 4 + r) * D_ + n0 + m] = oc[r];
  }
}

extern "C" void kernel_launch(void* const* d_in, const int* in_sizes, int n_in,
                              void* d_out, int out_size, void* d_ws, size_t ws_size,
                              hipStream_t stream) {
  const float* Q = (const float*)d_in[0];
  const float* K = (const float*)d_in[1];
  const float* V = (const float*)d_in[2];
  float* O = (float*)d_out;                          // output first
  float* A = O + (size_t)B_ * H_ * S_ * D_;          // then attn
  dim3 grid(S_ / QT, B_ * H_);
  attn_fused<<<grid, NW * 64, 0, stream>>>(Q, K, V, O, A);
}

// Round 2
// 408.493 us; speedup vs baseline: 1.2099x; 1.2099x over previous
//
#include <hip/hip_runtime.h>
#include <hip/hip_bf16.h>

#define B_ 8
#define H_ 8
#define S_ 1024
#define D_ 64

typedef __attribute__((ext_vector_type(8))) short bf16x8;
typedef __attribute__((ext_vector_type(4))) float f32x4;

__device__ __forceinline__ short f2bf(float f) {
  union { float f; unsigned u; } x; x.f = f;
  unsigned r = (x.u + 0x7FFFu + ((x.u >> 16) & 1u)) >> 16;
  return (short)r;
}

// ---------------- pre-pass 1: f32 -> bf16, layout preserved ----------------
__global__ __launch_bounds__(256) void cvt_bf16(const float* __restrict__ in,
                                                short* __restrict__ out) {
  const size_t i = ((size_t)blockIdx.x * 256 + threadIdx.x) * 8;
  float4 a = *(const float4*)(in + i);
  float4 b = *(const float4*)(in + i + 4);
  bf16x8 f;
  f[0] = f2bf(a.x); f[1] = f2bf(a.y); f[2] = f2bf(a.z); f[3] = f2bf(a.w);
  f[4] = f2bf(b.x); f[5] = f2bf(b.y); f[6] = f2bf(b.z); f[7] = f2bf(b.w);
  *(bf16x8*)(out + i) = f;
}

// ------------- pre-pass 2: V[bh][s][d] f32 -> Vt[bh][d][s] bf16 -------------
__global__ __launch_bounds__(256) void vtrans(const float* __restrict__ V,
                                              short* __restrict__ Vt) {
  const int bh = blockIdx.y;
  const int s0 = blockIdx.x * 64;
  __shared__ float tile[64][65];
  const float* Vb = V + ((size_t)bh * S_ + s0) * D_;
  const int t = threadIdx.x;
  {
    const int rbase = t >> 4;        // 0..15
    const int c4 = (t & 15) * 4;     // 0..60
    #pragma unroll
    for (int i = 0; i < 4; ++i) {
      const int row = i * 16 + rbase;
      float4 v = *(const float4*)(Vb + (size_t)row * D_ + c4);
      tile[row][c4 + 0] = v.x; tile[row][c4 + 1] = v.y;
      tile[row][c4 + 2] = v.z; tile[row][c4 + 3] = v.w;
    }
  }
  __syncthreads();
  const int d = t >> 2;              // 0..63
  const int sq = (t & 3) * 16;       // 0,16,32,48
  short* op = Vt + ((size_t)bh * D_ + d) * S_ + s0 + sq;
  bf16x8 a, b;
  #pragma unroll
  for (int j = 0; j < 8; ++j) {
    a[j] = f2bf(tile[sq + j][d]);
    b[j] = f2bf(tile[sq + 8 + j][d]);
  }
  *(bf16x8*)op = a;
  *(bf16x8*)(op + 8) = b;
}

// ------------------------------ main kernel --------------------------------
constexpr int QT  = 16;             // q rows per workgroup
constexpr int NW  = 4;              // waves per workgroup
constexpr int TPW = (S_ / 16) / NW; // 16 k-tiles per wave
constexpr int PPAD = 8;

__global__ __launch_bounds__(256) void attn_fused(
    const short* __restrict__ Qb16, const short* __restrict__ Kb16,
    const short* __restrict__ Vt, const float* __restrict__ V_unused,
    float* __restrict__ O, float* __restrict__ A)
{
  const int bh   = blockIdx.y;
  const int q0   = blockIdx.x * QT;
  const int tid  = threadIdx.x;
  const int wave = tid >> 6;
  const int lane = tid & 63;
  const int m    = lane & 15;
  const int quad = lane >> 4;

  const short* Qb  = Qb16 + (size_t)bh * S_ * D_;
  const short* Kb  = Kb16 + (size_t)bh * S_ * D_;
  const short* Vtb = Vt   + (size_t)bh * D_ * S_;
  float* Ob = O + (size_t)bh * S_ * D_;
  float* Ab = A + (size_t)bh * S_ * S_;

  __shared__ float redmax[NW][QT];
  __shared__ float redsum[NW][QT];
  __shared__ short pbuf[QT][S_ + PPAD];

  // Q fragments: A[m][k=quad*8+j (+32)]
  bf16x8 qf0, qf1;
  {
    const short* qp = Qb + (size_t)(q0 + m) * D_ + quad * 8;
    qf0 = *(const bf16x8*)qp;
    qf1 = *(const bf16x8*)(qp + 32);
  }

  // ---- scores ----
  f32x4 acc[TPW];
  #pragma unroll
  for (int t = 0; t < TPW; ++t) {
    const int kt = t * NW + wave;
    const short* kp = Kb + (size_t)(kt * 16 + m) * D_ + quad * 8;
    bf16x8 kf0 = *(const bf16x8*)kp;
    bf16x8 kf1 = *(const bf16x8*)(kp + 32);
    f32x4 c = {0.f, 0.f, 0.f, 0.f};
    c = __builtin_amdgcn_mfma_f32_16x16x32_bf16(qf0, kf0, c, 0, 0, 0);
    c = __builtin_amdgcn_mfma_f32_16x16x32_bf16(qf1, kf1, c, 0, 0, 0);
    acc[t] = c * 0.125f;
  }

  // ---- row max ----
  float tmp4[4];
  #pragma unroll
  for (int r = 0; r < 4; ++r) {
    float v = acc[0][r];
    #pragma unroll
    for (int t = 1; t < TPW; ++t) v = fmaxf(v, acc[t][r]);
    v = fmaxf(v, __shfl_xor(v, 1));
    v = fmaxf(v, __shfl_xor(v, 2));
    v = fmaxf(v, __shfl_xor(v, 4));
    v = fmaxf(v, __shfl_xor(v, 8));
    tmp4[r] = v;
  }
  if (m == 0) {
    #pragma unroll
    for (int r = 0; r < 4; ++r) redmax[wave][quad * 4 + r] = tmp4[r];
  }
  __syncthreads();

  // ---- exp + row sum ----
  #pragma unroll
  for (int r = 0; r < 4; ++r) {
    const int row = quad * 4 + r;
    const float gm = fmaxf(fmaxf(redmax[0][row], redmax[1][row]),
                           fmaxf(redmax[2][row], redmax[3][row]));
    float s = 0.f;
    #pragma unroll
    for (int t = 0; t < TPW; ++t) {
      float p = __builtin_exp2f((acc[t][r] - gm) * 1.4426950408889634f);
      acc[t][r] = p;
      s += p;
    }
    s += __shfl_xor(s, 1);
    s += __shfl_xor(s, 2);
    s += __shfl_xor(s, 4);
    s += __shfl_xor(s, 8);
    tmp4[r] = s;
  }
  if (m == 0) {
    #pragma unroll
    for (int r = 0; r < 4; ++r) redsum[wave][quad * 4 + r] = tmp4[r];
  }
  __syncthreads();

  float rinv[4];
  #pragma unroll
  for (int r = 0; r < 4; ++r) {
    const int row = quad * 4 + r;
    rinv[r] = 1.f / ((redsum[0][row] + redsum[1][row]) +
                     (redsum[2][row] + redsum[3][row]));
  }

  // ---- normalize: attn global write (nontemporal) + P bf16 to LDS ----
  #pragma unroll
  for (int t = 0; t < TPW; ++t) {
    const int kt = t * NW + wave;
    #pragma unroll
    for (int r = 0; r < 4; ++r) {
      const int row = quad * 4 + r;
      const float p = acc[t][r] * rinv[r];
      __builtin_nontemporal_store(p, &Ab[(size_t)(q0 + row) * S_ + kt * 16 + m]);
      pbuf[row][kt * 16 + m] = f2bf(p);
    }
  }
  __syncthreads();

  // ---- O = P · V, wave w owns d-cols [16w, 16w+16), 2 acc chains ----
  f32x4 oc0 = {0.f, 0.f, 0.f, 0.f};
  f32x4 oc1 = {0.f, 0.f, 0.f, 0.f};
  const int n0 = wave * 16;
  const short* vrow = Vtb + (size_t)(n0 + m) * S_;
  for (int kc = 0; kc < S_ / 32; kc += 2) {
    bf16x8 af0 = *(const bf16x8*)&pbuf[m][kc * 32 + quad * 8];
    bf16x8 bv0 = *(const bf16x8*)(vrow + kc * 32 + quad * 8);
    oc0 = __builtin_amdgcn_mfma_f32_16x16x32_bf16(af0, bv0, oc0, 0, 0, 0);
    bf16x8 af1 = *(const bf16x8*)&pbuf[m][(kc + 1) * 32 + quad * 8];
    bf16x8 bv1 = *(const bf16x8*)(vrow + (kc + 1) * 32 + quad * 8);
    oc1 = __builtin_amdgcn_mfma_f32_16x16x32_bf16(af1, bv1, oc1, 0, 0, 0);
  }
  #pragma unroll
  for (int r = 0; r < 4; ++r) {
    Ob[(size_t)(q0 + quad * 4 + r) * D_ + n0 + m] = oc0[r] + oc1[r];
  }
}

extern "C" void kernel_launch(void* const* d_in, const int* in_sizes, int n_in,
                              void* d_out, int out_size, void* d_ws, size_t ws_size,
                              hipStream_t stream) {
  const float* Q = (const float*)d_in[0];
  const float* K = (const float*)d_in[1];
  const float* V = (const float*)d_in[2];
  float* O = (float*)d_out;
  float* A = O + (size_t)B_ * H_ * S_ * D_;

  const size_t NEL = (size_t)B_ * H_ * S_ * D_;  // 4194304
  short* Qbf = (short*)d_ws;
  short* Kbf = Qbf + NEL;
  short* Vtb = Kbf + NEL;

  const int cvt_blocks = (int)(NEL / 8 / 256);   // 2048
  cvt_bf16<<<cvt_blocks, 256, 0, stream>>>(Q, Qbf);
  cvt_bf16<<<cvt_blocks, 256, 0, stream>>>(K, Kbf);
  vtrans<<<dim3(S_ / 64, B_ * H_), 256, 0, stream>>>(V, Vtb);

  dim3 grid(S_ / QT, B_ * H_);
  attn_fused<<<grid, NW * 64, 0, stream>>>(Qbf, Kbf, Vtb, V, O, A);
}